// Round 16
// baseline (202.978 us; speedup 1.0000x reference)
//
#include <hip/hip_runtime.h>
#include <hip/hip_fp16.h>

#define NN   50000
#define NE   800000
#define IND  256
#define HIDD 64
#define OUTD 64
#define NH1  4
#define NH2  1
#define NEG  0.2f

#define NBUK 196          // ceil(NN / 256)
#define NCHK 256          // edge chunks
#define CE   3125         // NE / NCHK (exact)
#define MAXDEG 96         // LDS alpha cache depth (deg ~ Poisson(16))
#define SBUF 6144         // per-bucket sort buffer (avg bucket 4082, max ~4500)

typedef float f32x4 __attribute__((ext_vector_type(4)));
typedef short s16x8 __attribute__((ext_vector_type(8)));

__device__ __forceinline__ short bf16_rne(float f) {
    unsigned u = __float_as_uint(f);
    unsigned r = u + 0x7FFFu + ((u >> 16) & 1u);
    return (short)(r >> 16);
}

// edges packed as (src << 16) | dst  — both < 65536
// ====== count dst-buckets per chunk (+ weight transpose/round prologue) ======
__global__ void cnt1_k(const int* __restrict__ key, int* __restrict__ cnt,
                       const float* __restrict__ W1, const float* __restrict__ W2,
                       short* __restrict__ Wt1, short* __restrict__ Wt2) {
    __shared__ int lc[NBUK];
    int tid = threadIdx.x, chunk = blockIdx.x;
    for (int idx = chunk * 256 + tid; idx < IND * IND + IND * OUTD; idx += NCHK * 256) {
        if (idx < IND * IND) {
            int k = idx / IND, n = idx - k * IND;
            Wt1[(size_t)n * IND + k] = bf16_rne(W1[idx]);
        } else {
            int i2 = idx - IND * IND;
            int k = i2 / OUTD, n = i2 - k * OUTD;
            Wt2[(size_t)n * IND + k] = bf16_rne(W2[i2]);
        }
    }
    for (int j = tid; j < NBUK; j += 256) lc[j] = 0;
    __syncthreads();
    const int* kc = key + (size_t)chunk * CE;
    for (int t = tid; t < CE; t += 256) atomicAdd(&lc[kc[t] >> 8], 1);
    __syncthreads();
    for (int j = tid; j < NBUK; j += 256) cnt[j * NCHK + chunk] = lc[j];
}

// one wave per bucket: exclusive scan of its 256 chunk counts; bucket totals out
__global__ void scanC_k(int* __restrict__ cnt, int* __restrict__ buktot) {
    int b    = blockIdx.x * 4 + (threadIdx.x >> 6);
    int lane = threadIdx.x & 63;
    if (b >= NBUK) return;
    int base = b * NCHK + lane * 4;
    int4 v = *(int4*)&cnt[base];
    int s0 = v.x, s1 = s0 + v.y, s2 = s1 + v.z, s3 = s2 + v.w;
    int inc = s3;
    for (int o = 1; o < 64; o <<= 1) {
        int t = __shfl_up(inc, o);
        if (lane >= o) inc += t;
    }
    int excl = inc - s3;
    int4 w;
    w.x = excl; w.y = excl + s0; w.z = excl + s1; w.w = excl + s2;
    *(int4*)&cnt[base] = w;
    if (lane == 63) buktot[b] = inc;
}

// scatter by dst-bucket (packed); bucket bases computed in-block from buktot
__global__ void fill1_k(const int* __restrict__ src, const int* __restrict__ dst,
                        const int* __restrict__ cnt, const int* __restrict__ buktot,
                        unsigned* __restrict__ eout) {
    __shared__ int cur[NBUK];
    __shared__ int tmp[256];
    int tid = threadIdx.x, chunk = blockIdx.x;
    int v = (tid < NBUK) ? buktot[tid] : 0;
    tmp[tid] = v;
    __syncthreads();
    for (int o = 1; o < 256; o <<= 1) {
        int add = (tid >= o) ? tmp[tid - o] : 0;
        __syncthreads();
        tmp[tid] += add;
        __syncthreads();
    }
    if (tid < NBUK) cur[tid] = cnt[tid * NCHK + chunk] + tmp[tid] - v;
    __syncthreads();
    size_t base = (size_t)chunk * CE;
    for (int t = tid; t < CE; t += 256) {
        int s = src[base + t], d = dst[base + t];
        int pos = atomicAdd(&cur[d >> 8], 1);
        eout[pos] = ((unsigned)s << 16) | (unsigned)d;
    }
}

// exact-dst group within each bucket + per-node insertion sort by src (in LDS)
__global__ void fill2_k(const unsigned* __restrict__ ein, const int* __restrict__ buktot,
                        int* __restrict__ off, int* __restrict__ deg,
                        int* __restrict__ src_sorted) {
    __shared__ int lh[256];
    __shared__ int tmp[256];
    __shared__ int cur[256];
    __shared__ unsigned short sbuf[SBUF];
    int tid = threadIdx.x, b = blockIdx.x;
    int v0 = (tid < NBUK) ? buktot[tid] : 0;
    tmp[tid] = v0;
    __syncthreads();
    for (int o = 1; o < 256; o <<= 1) {
        int add = (tid >= o) ? tmp[tid - o] : 0;
        __syncthreads();
        tmp[tid] += add;
        __syncthreads();
    }
    int beg = (b > 0) ? tmp[b - 1] : 0;
    int end = tmp[b];
    __syncthreads();
    int node0 = b << 8;
    int nE = end - beg;
    lh[tid] = 0;
    __syncthreads();
    for (int e = beg + tid; e < end; e += 256)
        atomicAdd(&lh[(int)(ein[e] & 0xFFFFu) - node0], 1);
    __syncthreads();
    int v = lh[tid];
    tmp[tid] = v;
    __syncthreads();
    for (int o = 1; o < 256; o <<= 1) {
        int add = (tid >= o) ? tmp[tid - o] : 0;
        __syncthreads();
        tmp[tid] += add;
        __syncthreads();
    }
    int excl = tmp[tid] - v;
    int node = node0 + tid;
    if (node < NN) { deg[node] = v; off[node] = beg + excl; }
    cur[tid] = excl;
    __syncthreads();
    if (nE <= SBUF) {
        // scatter src values into LDS at exact-dst positions
        for (int e = beg + tid; e < end; e += 256) {
            unsigned ed = ein[e];
            int r = atomicAdd(&cur[(int)(ed & 0xFFFFu) - node0], 1);
            sbuf[r] = (unsigned short)(ed >> 16);
        }
        __syncthreads();
        // per-node insertion sort by src (each thread owns its node's slice)
        for (int i = excl + 1; i < excl + v; ++i) {
            unsigned short key = sbuf[i];
            int j = i - 1;
            while (j >= excl && sbuf[j] > key) { sbuf[j + 1] = sbuf[j]; --j; }
            sbuf[j + 1] = key;
        }
        __syncthreads();
        // coalesced write-out
        for (int e = tid; e < nE; e += 256) src_sorted[beg + e] = sbuf[e];
    } else {
        // statistical-impossibility fallback: unsorted direct scatter
        for (int e = beg + tid; e < end; e += 256) {
            unsigned ed = ein[e];
            int r = atomicAdd(&cur[(int)(ed & 0xFFFFu) - node0], 1);
            src_sorted[beg + r] = (int)(ed >> 16);
        }
    }
}

// ===== MFMA GEMM layer 1: 64x256 tile, bf16 A and B, el/er fused =====
__global__ __launch_bounds__(256) void gemm_l1(const float* __restrict__ A,
                                               const short* __restrict__ Bt,
                                               const float* __restrict__ al,
                                               const float* __restrict__ ar,
                                               __half* __restrict__ C,
                                               float* __restrict__ el,
                                               float* __restrict__ er, int M) {
    const int K = 256;
    __shared__ short As[64][40];
    __shared__ short Bs[256][40];

    int tid  = threadIdx.x;
    int wid  = tid >> 6, lane = tid & 63;
    int wm   = (wid >> 1) * 32;
    int wn   = (wid & 1) * 128;
    int row0 = blockIdx.x * 64;

    int arow = tid >> 2;
    int aseg = (tid & 3) * 8;
    int mr   = lane & 15;
    int kg   = (lane >> 4) * 8;

    f32x4 acc[2][8];
#pragma unroll
    for (int i = 0; i < 2; ++i)
#pragma unroll
        for (int j = 0; j < 8; ++j) acc[i][j] = (f32x4)(0.f);

    for (int k0 = 0; k0 < K; k0 += 32) {
        {   // A: 64 rows x 32 k, bf16 RNE
            int r = row0 + arow;
            float v[8];
            if (r < M) {
                float4 f0 = *(const float4*)&A[(size_t)r * K + k0 + aseg];
                float4 f1 = *(const float4*)&A[(size_t)r * K + k0 + aseg + 4];
                v[0] = f0.x; v[1] = f0.y; v[2] = f0.z; v[3] = f0.w;
                v[4] = f1.x; v[5] = f1.y; v[6] = f1.z; v[7] = f1.w;
            } else {
#pragma unroll
                for (int q = 0; q < 8; ++q) v[q] = 0.f;
            }
            short hi[8];
#pragma unroll
            for (int q = 0; q < 8; ++q) hi[q] = bf16_rne(v[q]);
            *(s16x8*)&As[arow][aseg] = *(s16x8*)&hi[0];
        }
        {   // B: 256 n x 32 k
#pragma unroll
            for (int rep = 0; rep < 4; ++rep) {
                int n = rep * 64 + (tid >> 2);
                int ks = (tid & 3) * 8;
                *(s16x8*)&Bs[n][ks] = *(const s16x8*)&Bt[(size_t)n * K + k0 + ks];
            }
        }
        __syncthreads();

        s16x8 ah[2];
#pragma unroll
        for (int mi = 0; mi < 2; ++mi)
            ah[mi] = *(const s16x8*)&As[wm + mi * 16 + mr][kg];
#pragma unroll
        for (int ni = 0; ni < 8; ++ni) {
            s16x8 bhv = *(const s16x8*)&Bs[wn + ni * 16 + mr][kg];
#pragma unroll
            for (int mi = 0; mi < 2; ++mi)
                acc[mi][ni] = __builtin_amdgcn_mfma_f32_16x16x32_bf16(ah[mi], bhv, acc[mi][ni], 0, 0, 0);
        }
        __syncthreads();
    }

    float av[8], rv[8];
#pragma unroll
    for (int ni = 0; ni < 8; ++ni) {
        int c = wn + ni * 16 + mr;
        av[ni] = al[c];
        rv[ni] = ar[c];
    }
    int h0 = wn >> 6;

#pragma unroll
    for (int mi = 0; mi < 2; ++mi) {
#pragma unroll
        for (int r4 = 0; r4 < 4; ++r4) {
            int rr = row0 + wm + mi * 16 + (lane >> 4) * 4 + r4;
            if (rr < M) {
#pragma unroll
                for (int ni = 0; ni < 8; ++ni)
                    C[(size_t)rr * 256 + wn + ni * 16 + mr] = __float2half(acc[mi][ni][r4]);
            }
            float e0 = 0.f, e1 = 0.f, f0 = 0.f, f1 = 0.f;
#pragma unroll
            for (int ni = 0; ni < 4; ++ni) {
                e0 += acc[mi][ni][r4] * av[ni];
                f0 += acc[mi][ni][r4] * rv[ni];
            }
#pragma unroll
            for (int ni = 4; ni < 8; ++ni) {
                e1 += acc[mi][ni][r4] * av[ni];
                f1 += acc[mi][ni][r4] * rv[ni];
            }
#pragma unroll
            for (int o = 1; o <= 8; o <<= 1) {
                e0 += __shfl_xor(e0, o); e1 += __shfl_xor(e1, o);
                f0 += __shfl_xor(f0, o); f1 += __shfl_xor(f1, o);
            }
            if (mr == 0 && rr < M) {
                el[rr * 4 + h0]     = e0;
                el[rr * 4 + h0 + 1] = e1;
                er[rr * 4 + h0]     = f0;
                er[rr * 4 + h0 + 1] = f1;
            }
        }
    }
}

// ================= MFMA GEMM layer 2: bf16 A and B, 1-term =================
__global__ __launch_bounds__(256) void gemm_l2(const short* __restrict__ A,
                                               const short* __restrict__ Bt,
                                               const float* __restrict__ al,
                                               const float* __restrict__ ar,
                                               __half* __restrict__ C,
                                               float* __restrict__ el,
                                               float* __restrict__ er, int M) {
    const int K = 256;
    __shared__ short As[128][40];
    __shared__ short Bs[64][40];

    int tid  = threadIdx.x;
    int wid  = tid >> 6, lane = tid & 63;
    int wm   = wid * 32;
    int row0 = blockIdx.x * 128;

    int arow = tid >> 1;
    int aseg = (tid & 1) * 16;
    int mr   = lane & 15;
    int kg   = (lane >> 4) * 8;

    f32x4 acc[2][4];
#pragma unroll
    for (int i = 0; i < 2; ++i)
#pragma unroll
        for (int j = 0; j < 4; ++j) acc[i][j] = (f32x4)(0.f);

    for (int k0 = 0; k0 < K; k0 += 32) {
        {
            int r = row0 + arow;
            if (r < M) {
                *(s16x8*)&As[arow][aseg]     = *(const s16x8*)&A[(size_t)r * K + k0 + aseg];
                *(s16x8*)&As[arow][aseg + 8] = *(const s16x8*)&A[(size_t)r * K + k0 + aseg + 8];
            } else {
                s16x8 z = (s16x8)(short)0;
                *(s16x8*)&As[arow][aseg]     = z;
                *(s16x8*)&As[arow][aseg + 8] = z;
            }
        }
        {
            int n  = tid >> 2;
            int ks = (tid & 3) * 8;
            *(s16x8*)&Bs[n][ks] = *(const s16x8*)&Bt[(size_t)n * K + k0 + ks];
        }
        __syncthreads();

        s16x8 av_[2];
#pragma unroll
        for (int mi = 0; mi < 2; ++mi)
            av_[mi] = *(const s16x8*)&As[wm + mi * 16 + mr][kg];
#pragma unroll
        for (int ni = 0; ni < 4; ++ni) {
            s16x8 bhv = *(const s16x8*)&Bs[ni * 16 + mr][kg];
#pragma unroll
            for (int mi = 0; mi < 2; ++mi)
                acc[mi][ni] = __builtin_amdgcn_mfma_f32_16x16x32_bf16(av_[mi], bhv, acc[mi][ni], 0, 0, 0);
        }
        __syncthreads();
    }

    float av[4], rv[4];
#pragma unroll
    for (int ni = 0; ni < 4; ++ni) {
        int c = ni * 16 + mr;
        av[ni] = al[c];
        rv[ni] = ar[c];
    }

#pragma unroll
    for (int mi = 0; mi < 2; ++mi) {
#pragma unroll
        for (int r4 = 0; r4 < 4; ++r4) {
            int rr = row0 + wm + mi * 16 + (lane >> 4) * 4 + r4;
            if (rr < M) {
#pragma unroll
                for (int ni = 0; ni < 4; ++ni)
                    C[(size_t)rr * 64 + ni * 16 + mr] = __float2half(acc[mi][ni][r4]);
            }
            float e0 = 0.f, f0 = 0.f;
#pragma unroll
            for (int ni = 0; ni < 4; ++ni) {
                e0 += acc[mi][ni][r4] * av[ni];
                f0 += acc[mi][ni][r4] * rv[ni];
            }
#pragma unroll
            for (int o = 1; o <= 8; o <<= 1) {
                e0 += __shfl_xor(e0, o);
                f0 += __shfl_xor(f0, o);
            }
            if (mr == 0 && rr < M) { el[rr] = e0; er[rr] = f0; }
        }
    }
}

// ====== fused softmax (no-max) + aggregation, layer 1 (H=4, D=64) ======
__global__ void agg_sm_l1(const __half* __restrict__ feat, const float* __restrict__ el,
                          const float* __restrict__ er, const int* __restrict__ src_sorted,
                          const int* __restrict__ off, const int* __restrict__ deg,
                          const float* __restrict__ bias, short* __restrict__ out) {
    __shared__ float alds[4][MAXDEG * 4];
    int w    = threadIdx.x >> 6;
    int wid  = blockIdx.x * 4 + w;
    int lane = threadIdx.x & 63;
    if (wid >= NN) return;
    int e   = lane >> 5;
    int c8  = (lane & 31) * 8;
    int h   = (lane & 31) >> 3;
    int k   = lane & 7;
    int sub = e * 8 + k;
    int beg = off[wid], dg = deg[wid];
    float erdh = er[(size_t)wid * 4 + h];

    float sum = 0.f;
    for (int p = sub; p < dg; p += 16) {
        int s = src_sorted[beg + p];
        float x = el[(size_t)s * 4 + h] + erdh;
        x = (x >= 0.f) ? x : NEG * x;
        float ex = __expf(x);
        if (p < MAXDEG) alds[w][p * 4 + h] = ex;
        sum += ex;
    }
    sum += __shfl_xor(sum, 1);
    sum += __shfl_xor(sum, 2);
    sum += __shfl_xor(sum, 4);
    sum += __shfl_xor(sum, 32);
    float inv = (dg > 0) ? 1.f / sum : 0.f;

    float acc[8] = {};
    int p = e;
    for (; p + 2 < dg; p += 4) {
        int s0 = src_sorted[beg + p];
        int s1 = src_sorted[beg + p + 2];
        float a0, a1;
        if (p < MAXDEG) a0 = alds[w][p * 4 + h];
        else {
            float x = el[(size_t)s0 * 4 + h] + erdh;
            x = (x >= 0.f) ? x : NEG * x;
            a0 = __expf(x);
        }
        if (p + 2 < MAXDEG) a1 = alds[w][(p + 2) * 4 + h];
        else {
            float x = el[(size_t)s1 * 4 + h] + erdh;
            x = (x >= 0.f) ? x : NEG * x;
            a1 = __expf(x);
        }
        float4 r0 = *(const float4*)&feat[(size_t)s0 * 256 + c8];
        float4 r1 = *(const float4*)&feat[(size_t)s1 * 256 + c8];
        __half2* h0 = (__half2*)&r0;
        __half2* h1 = (__half2*)&r1;
#pragma unroll
        for (int q = 0; q < 4; ++q) {
            float2 f0 = __half22float2(h0[q]);
            float2 f1 = __half22float2(h1[q]);
            acc[2 * q]     += a0 * f0.x + a1 * f1.x;
            acc[2 * q + 1] += a0 * f0.y + a1 * f1.y;
        }
    }
    for (; p < dg; p += 2) {
        int s = src_sorted[beg + p];
        float a;
        if (p < MAXDEG) a = alds[w][p * 4 + h];
        else {
            float x = el[(size_t)s * 4 + h] + erdh;
            x = (x >= 0.f) ? x : NEG * x;
            a = __expf(x);
        }
        float4 raw = *(const float4*)&feat[(size_t)s * 256 + c8];
        __half2* hh = (__half2*)&raw;
#pragma unroll
        for (int q = 0; q < 4; ++q) {
            float2 f = __half22float2(hh[q]);
            acc[2 * q]     += a * f.x;
            acc[2 * q + 1] += a * f.y;
        }
    }
#pragma unroll
    for (int q = 0; q < 8; ++q) acc[q] += __shfl_xor(acc[q], 32);
    if (e == 0) {
        short ob[8];
#pragma unroll
        for (int q = 0; q < 8; ++q) {
            float v = fmaxf(acc[q] * inv + bias[c8 + q], 0.f);
            ob[q] = bf16_rne(v);
        }
        *(s16x8*)&out[(size_t)wid * 256 + c8] = *(s16x8*)&ob[0];
    }
}

// ====== fused softmax (no-max) + aggregation, layer 2 (H=1, D=64) ======
__global__ void agg_sm_l2(const __half* __restrict__ feat, const float* __restrict__ el,
                          const float* __restrict__ er, const int* __restrict__ src_sorted,
                          const int* __restrict__ off, const int* __restrict__ deg,
                          const float* __restrict__ bias, float* __restrict__ out) {
    __shared__ float alds[4][MAXDEG];
    int w    = threadIdx.x >> 6;
    int wid  = blockIdx.x * 4 + w;
    int lane = threadIdx.x & 63;
    if (wid >= NN) return;
    int e   = lane >> 3;
    int c8  = (lane & 7) * 8;
    int beg = off[wid], dg = deg[wid];
    float erd = er[wid];

    float sum = 0.f;
    for (int p = lane; p < dg; p += 64) {
        int s = src_sorted[beg + p];
        float x = el[s] + erd;
        x = (x >= 0.f) ? x : NEG * x;
        float ex = __expf(x);
        if (p < MAXDEG) alds[w][p] = ex;
        sum += ex;
    }
#pragma unroll
    for (int o = 1; o <= 32; o <<= 1) sum += __shfl_xor(sum, o);
    float inv = (dg > 0) ? 1.f / sum : 0.f;

    float acc[8] = {};
    for (int p = 0; p < dg; p += 8) {
        if (p + e < dg) {
            int s = src_sorted[beg + p + e];
            float a;
            if (p + e < MAXDEG) a = alds[w][p + e];
            else {
                float x = el[s] + erd;
                x = (x >= 0.f) ? x : NEG * x;
                a = __expf(x);
            }
            float4 raw = *(const float4*)&feat[(size_t)s * 64 + c8];
            __half2* hh = (__half2*)&raw;
#pragma unroll
            for (int q = 0; q < 4; ++q) {
                float2 f = __half22float2(hh[q]);
                acc[2 * q]     += a * f.x;
                acc[2 * q + 1] += a * f.y;
            }
        }
    }
#pragma unroll
    for (int o = 8; o <= 32; o <<= 1)
#pragma unroll
        for (int q = 0; q < 8; ++q) acc[q] += __shfl_xor(acc[q], o);
    if (e == 0) {
        float4 b0 = *(const float4*)&bias[c8];
        float4 b1 = *(const float4*)&bias[c8 + 4];
        float4 o0 = make_float4(acc[0] * inv + b0.x, acc[1] * inv + b0.y,
                                acc[2] * inv + b0.z, acc[3] * inv + b0.w);
        float4 o1 = make_float4(acc[4] * inv + b1.x, acc[5] * inv + b1.y,
                                acc[6] * inv + b1.z, acc[7] * inv + b1.w);
        *(float4*)&out[(size_t)wid * 64 + c8]     = o0;
        *(float4*)&out[(size_t)wid * 64 + c8 + 4] = o1;
    }
}

extern "C" void kernel_launch(void* const* d_in, const int* in_sizes, int n_in,
                              void* d_out, int out_size, void* d_ws, size_t ws_size,
                              hipStream_t stream) {
    const float* features = (const float*)d_in[0];
    const int*   src      = (const int*)  d_in[1];
    const int*   dst      = (const int*)  d_in[2];
    const float* W1       = (const float*)d_in[3];
    const float* al1      = (const float*)d_in[4];
    const float* ar1      = (const float*)d_in[5];
    const float* b1       = (const float*)d_in[6];
    const float* W2       = (const float*)d_in[7];
    const float* al2      = (const float*)d_in[8];
    const float* ar2      = (const float*)d_in[9];
    const float* b2       = (const float*)d_in[10];
    float* out = (float*)d_out;

    // ---- workspace layout (byte offsets) ----
    char* base = (char*)d_ws;
    size_t o = 0;
    __half* feat1h = (__half*)(base + o); o += (size_t)NN * 256 * 2;
    short*  h1b    = (short*) (base + o); o += (size_t)NN * 256 * 2;
    float*  el1 = (float*)(base + o); o += (size_t)NN * 4 * 4;
    float*  er1 = (float*)(base + o); o += (size_t)NN * 4 * 4;
    float*  el2 = (float*)(base + o); o += (size_t)NN * 4;
    float*  er2 = (float*)(base + o); o += (size_t)NN * 4;
    int* deg        = (int*)(base + o); o += (size_t)NN * 4;
    int* off        = (int*)(base + o); o += (size_t)NN * 4;
    int* src_sorted = (int*)(base + o); o += (size_t)NE * 4;
    int* cnt        = (int*)(base + o); o += (size_t)NBUK * NCHK * 4;
    int* buktot     = (int*)(base + o); o += 1024;
    unsigned* ebufD = (unsigned*)(base + o); o += (size_t)NE * 4;
    short* Wt1 = (short*)(base + o); o += (size_t)IND * IND * 2;
    short* Wt2 = (short*)(base + o); o += (size_t)OUTD * IND * 2;

    __half* feat2h = feat1h;

    // ---- CSR build (4 launches; dst-coarse + exact/sort) ----
    cnt1_k <<<NCHK, 256, 0, stream>>>(dst, cnt, W1, W2, Wt1, Wt2);
    scanC_k<<<(NBUK + 3) / 4, 256, 0, stream>>>(cnt, buktot);
    fill1_k<<<NCHK, 256, 0, stream>>>(src, dst, cnt, buktot, ebufD);
    fill2_k<<<NBUK, 256, 0, stream>>>(ebufD, buktot, off, deg, src_sorted);

    // ======== layer 1 ========
    gemm_l1<<<(NN + 63) / 64, 256, 0, stream>>>(features, Wt1, al1, ar1,
                                                feat1h, el1, er1, NN);
    agg_sm_l1<<<(NN + 3) / 4, 256, 0, stream>>>(feat1h, el1, er1, src_sorted, off, deg,
                                                b1, h1b);

    // ======== layer 2 ========
    gemm_l2<<<(NN + 127) / 128, 256, 0, stream>>>(h1b, Wt2, al2, ar2,
                                                  feat2h, el2, er2, NN);
    agg_sm_l2<<<(NN + 3) / 4, 256, 0, stream>>>(feat2h, el2, er2, src_sorted, off, deg,
                                                b2, out);
}

// Round 17
// 183.614 us; speedup vs baseline: 1.1055x; 1.1055x over previous
//
#include <hip/hip_runtime.h>
#include <hip/hip_fp16.h>

#define NN   50000
#define NE   800000
#define IND  256
#define HIDD 64
#define OUTD 64
#define NH1  4
#define NH2  1
#define NEG  0.2f

#define NBUK 196          // ceil(NN / 256)
#define NCHK 256          // edge chunks
#define CE   3125         // NE / NCHK (exact)
#define MAXDEG 96         // LDS alpha cache depth (deg ~ Poisson(16))

typedef float f32x4 __attribute__((ext_vector_type(4)));
typedef short s16x8 __attribute__((ext_vector_type(8)));

__device__ __forceinline__ short bf16_rne(float f) {
    unsigned u = __float_as_uint(f);
    unsigned r = u + 0x7FFFu + ((u >> 16) & 1u);
    return (short)(r >> 16);
}

// ====== pass-1 count (+ independent weight transpose/round prologue) ======
__global__ void cnt1a_k(const int* __restrict__ key, int* __restrict__ cnt,
                        const float* __restrict__ W1, const float* __restrict__ W2,
                        short* __restrict__ Wt1, short* __restrict__ Wt2) {
    __shared__ int lc[NBUK];
    int tid = threadIdx.x, chunk = blockIdx.x;
    // weight prep: grid-stride over both W matrices (independent of counts)
    for (int idx = chunk * 256 + tid; idx < IND * IND + IND * OUTD; idx += NCHK * 256) {
        if (idx < IND * IND) {
            int k = idx / IND, n = idx - k * IND;
            Wt1[(size_t)n * IND + k] = bf16_rne(W1[idx]);
        } else {
            int i2 = idx - IND * IND;
            int k = i2 / OUTD, n = i2 - k * OUTD;
            Wt2[(size_t)n * IND + k] = bf16_rne(W2[i2]);
        }
    }
    for (int j = tid; j < NBUK; j += 256) lc[j] = 0;
    __syncthreads();
    const int* kc = key + (size_t)chunk * CE;
    for (int t = tid; t < CE; t += 256) atomicAdd(&lc[kc[t] >> 8], 1);
    __syncthreads();
    for (int j = tid; j < NBUK; j += 256) cnt[j * NCHK + chunk] = lc[j];
}

__global__ void cnt1b_k(const int2* __restrict__ ein, int* __restrict__ cnt) {
    __shared__ int lc[NBUK];
    int tid = threadIdx.x, chunk = blockIdx.x;
    for (int j = tid; j < NBUK; j += 256) lc[j] = 0;
    __syncthreads();
    const int2* ec = ein + (size_t)chunk * CE;
    for (int t = tid; t < CE; t += 256) atomicAdd(&lc[ec[t].y >> 8], 1);
    __syncthreads();
    for (int j = tid; j < NBUK; j += 256) cnt[j * NCHK + chunk] = lc[j];
}

// one wave per bucket: exclusive scan of its 256 chunk counts; bucket totals out
__global__ void scanC_k(int* __restrict__ cnt, int* __restrict__ buktot) {
    int b    = blockIdx.x * 4 + (threadIdx.x >> 6);
    int lane = threadIdx.x & 63;
    if (b >= NBUK) return;
    int base = b * NCHK + lane * 4;
    int4 v = *(int4*)&cnt[base];
    int s0 = v.x, s1 = s0 + v.y, s2 = s1 + v.z, s3 = s2 + v.w;
    int inc = s3;
    for (int o = 1; o < 64; o <<= 1) {
        int t = __shfl_up(inc, o);
        if (lane >= o) inc += t;
    }
    int excl = inc - s3;
    int4 w;
    w.x = excl; w.y = excl + s0; w.z = excl + s1; w.w = excl + s2;
    *(int4*)&cnt[base] = w;
    if (lane == 63) buktot[b] = inc;
}

// pass-1 scatter; bucket bases computed in-block from buktot
__global__ void fill1a_k(const int* __restrict__ src, const int* __restrict__ dst,
                         const int* __restrict__ cnt, const int* __restrict__ buktot,
                         int2* __restrict__ eout) {
    __shared__ int cur[NBUK];
    __shared__ int tmp[256];
    int tid = threadIdx.x, chunk = blockIdx.x;
    int v = (tid < NBUK) ? buktot[tid] : 0;
    tmp[tid] = v;
    __syncthreads();
    for (int o = 1; o < 256; o <<= 1) {
        int add = (tid >= o) ? tmp[tid - o] : 0;
        __syncthreads();
        tmp[tid] += add;
        __syncthreads();
    }
    if (tid < NBUK) cur[tid] = cnt[tid * NCHK + chunk] + tmp[tid] - v;
    __syncthreads();
    size_t base = (size_t)chunk * CE;
    for (int t = tid; t < CE; t += 256) {
        int s = src[base + t], d = dst[base + t];
        int pos = atomicAdd(&cur[s >> 8], 1);
        eout[pos] = make_int2(s, d);
    }
}

__global__ void fill1b_k(const int2* __restrict__ ein, const int* __restrict__ cnt,
                         const int* __restrict__ buktot, int2* __restrict__ eout) {
    __shared__ int cur[NBUK];
    __shared__ int tmp[256];
    int tid = threadIdx.x, chunk = blockIdx.x;
    int v = (tid < NBUK) ? buktot[tid] : 0;
    tmp[tid] = v;
    __syncthreads();
    for (int o = 1; o < 256; o <<= 1) {
        int add = (tid >= o) ? tmp[tid - o] : 0;
        __syncthreads();
        tmp[tid] += add;
        __syncthreads();
    }
    if (tid < NBUK) cur[tid] = cnt[tid * NCHK + chunk] + tmp[tid] - v;
    __syncthreads();
    const int2* ec = ein + (size_t)chunk * CE;
    for (int t = tid; t < CE; t += 256) {
        int2 e = ec[t];
        int pos = atomicAdd(&cur[e.y >> 8], 1);
        eout[pos] = e;
    }
}

// exact-dst pass within each bucket (bucket range from in-block buktot scan)
__global__ void fill2_k(const int2* __restrict__ ein, const int* __restrict__ buktot,
                        int* __restrict__ off, int* __restrict__ deg,
                        int* __restrict__ src_sorted) {
    __shared__ int lh[256];
    __shared__ int tmp[256];
    __shared__ int cur[256];
    int tid = threadIdx.x, b = blockIdx.x;
    int v0 = (tid < NBUK) ? buktot[tid] : 0;
    tmp[tid] = v0;
    __syncthreads();
    for (int o = 1; o < 256; o <<= 1) {
        int add = (tid >= o) ? tmp[tid - o] : 0;
        __syncthreads();
        tmp[tid] += add;
        __syncthreads();
    }
    int beg = (b > 0) ? tmp[b - 1] : 0;
    int end = tmp[b];
    __syncthreads();
    int node0 = b << 8;
    lh[tid] = 0;
    __syncthreads();
    for (int e = beg + tid; e < end; e += 256)
        atomicAdd(&lh[ein[e].y - node0], 1);
    __syncthreads();
    int v = lh[tid];
    tmp[tid] = v;
    __syncthreads();
    for (int o = 1; o < 256; o <<= 1) {
        int add = (tid >= o) ? tmp[tid - o] : 0;
        __syncthreads();
        tmp[tid] += add;
        __syncthreads();
    }
    int excl = tmp[tid] - v;
    int node = node0 + tid;
    if (node < NN) { deg[node] = v; off[node] = beg + excl; }
    cur[tid] = excl;
    __syncthreads();
    for (int e = beg + tid; e < end; e += 256) {
        int2 ed = ein[e];
        int r = atomicAdd(&cur[ed.y - node0], 1);
        src_sorted[beg + r] = ed.x;
    }
}

// ===== MFMA GEMM layer 1: 64x256 tile, bf16 A and B, el/er fused =====
__global__ __launch_bounds__(256) void gemm_l1(const float* __restrict__ A,
                                               const short* __restrict__ Bt,
                                               const float* __restrict__ al,
                                               const float* __restrict__ ar,
                                               __half* __restrict__ C,
                                               float* __restrict__ el,
                                               float* __restrict__ er, int M) {
    const int K = 256;
    __shared__ short As[64][40];
    __shared__ short Bs[256][40];

    int tid  = threadIdx.x;
    int wid  = tid >> 6, lane = tid & 63;
    int wm   = (wid >> 1) * 32;
    int wn   = (wid & 1) * 128;
    int row0 = blockIdx.x * 64;

    int arow = tid >> 2;
    int aseg = (tid & 3) * 8;
    int mr   = lane & 15;
    int kg   = (lane >> 4) * 8;

    f32x4 acc[2][8];
#pragma unroll
    for (int i = 0; i < 2; ++i)
#pragma unroll
        for (int j = 0; j < 8; ++j) acc[i][j] = (f32x4)(0.f);

    for (int k0 = 0; k0 < K; k0 += 32) {
        {   // A: 64 rows x 32 k, bf16 RNE
            int r = row0 + arow;
            float v[8];
            if (r < M) {
                float4 f0 = *(const float4*)&A[(size_t)r * K + k0 + aseg];
                float4 f1 = *(const float4*)&A[(size_t)r * K + k0 + aseg + 4];
                v[0] = f0.x; v[1] = f0.y; v[2] = f0.z; v[3] = f0.w;
                v[4] = f1.x; v[5] = f1.y; v[6] = f1.z; v[7] = f1.w;
            } else {
#pragma unroll
                for (int q = 0; q < 8; ++q) v[q] = 0.f;
            }
            short hi[8];
#pragma unroll
            for (int q = 0; q < 8; ++q) hi[q] = bf16_rne(v[q]);
            *(s16x8*)&As[arow][aseg] = *(s16x8*)&hi[0];
        }
        {   // B: 256 n x 32 k
#pragma unroll
            for (int rep = 0; rep < 4; ++rep) {
                int n = rep * 64 + (tid >> 2);
                int ks = (tid & 3) * 8;
                *(s16x8*)&Bs[n][ks] = *(const s16x8*)&Bt[(size_t)n * K + k0 + ks];
            }
        }
        __syncthreads();

        s16x8 ah[2];
#pragma unroll
        for (int mi = 0; mi < 2; ++mi)
            ah[mi] = *(const s16x8*)&As[wm + mi * 16 + mr][kg];
#pragma unroll
        for (int ni = 0; ni < 8; ++ni) {
            s16x8 bhv = *(const s16x8*)&Bs[wn + ni * 16 + mr][kg];
#pragma unroll
            for (int mi = 0; mi < 2; ++mi)
                acc[mi][ni] = __builtin_amdgcn_mfma_f32_16x16x32_bf16(ah[mi], bhv, acc[mi][ni], 0, 0, 0);
        }
        __syncthreads();
    }

    float av[8], rv[8];
#pragma unroll
    for (int ni = 0; ni < 8; ++ni) {
        int c = wn + ni * 16 + mr;
        av[ni] = al[c];
        rv[ni] = ar[c];
    }
    int h0 = wn >> 6;

#pragma unroll
    for (int mi = 0; mi < 2; ++mi) {
#pragma unroll
        for (int r4 = 0; r4 < 4; ++r4) {
            int rr = row0 + wm + mi * 16 + (lane >> 4) * 4 + r4;
            if (rr < M) {
#pragma unroll
                for (int ni = 0; ni < 8; ++ni)
                    C[(size_t)rr * 256 + wn + ni * 16 + mr] = __float2half(acc[mi][ni][r4]);
            }
            float e0 = 0.f, e1 = 0.f, f0 = 0.f, f1 = 0.f;
#pragma unroll
            for (int ni = 0; ni < 4; ++ni) {
                e0 += acc[mi][ni][r4] * av[ni];
                f0 += acc[mi][ni][r4] * rv[ni];
            }
#pragma unroll
            for (int ni = 4; ni < 8; ++ni) {
                e1 += acc[mi][ni][r4] * av[ni];
                f1 += acc[mi][ni][r4] * rv[ni];
            }
#pragma unroll
            for (int o = 1; o <= 8; o <<= 1) {
                e0 += __shfl_xor(e0, o); e1 += __shfl_xor(e1, o);
                f0 += __shfl_xor(f0, o); f1 += __shfl_xor(f1, o);
            }
            if (mr == 0 && rr < M) {
                el[rr * 4 + h0]     = e0;
                el[rr * 4 + h0 + 1] = e1;
                er[rr * 4 + h0]     = f0;
                er[rr * 4 + h0 + 1] = f1;
            }
        }
    }
}

// ================= MFMA GEMM layer 2: bf16 A and B, 1-term =================
__global__ __launch_bounds__(256) void gemm_l2(const short* __restrict__ A,
                                               const short* __restrict__ Bt,
                                               const float* __restrict__ al,
                                               const float* __restrict__ ar,
                                               __half* __restrict__ C,
                                               float* __restrict__ el,
                                               float* __restrict__ er, int M) {
    const int K = 256;
    __shared__ short As[128][40];
    __shared__ short Bs[64][40];

    int tid  = threadIdx.x;
    int wid  = tid >> 6, lane = tid & 63;
    int wm   = wid * 32;
    int row0 = blockIdx.x * 128;

    int arow = tid >> 1;
    int aseg = (tid & 1) * 16;
    int mr   = lane & 15;
    int kg   = (lane >> 4) * 8;

    f32x4 acc[2][4];
#pragma unroll
    for (int i = 0; i < 2; ++i)
#pragma unroll
        for (int j = 0; j < 4; ++j) acc[i][j] = (f32x4)(0.f);

    for (int k0 = 0; k0 < K; k0 += 32) {
        {
            int r = row0 + arow;
            if (r < M) {
                *(s16x8*)&As[arow][aseg]     = *(const s16x8*)&A[(size_t)r * K + k0 + aseg];
                *(s16x8*)&As[arow][aseg + 8] = *(const s16x8*)&A[(size_t)r * K + k0 + aseg + 8];
            } else {
                s16x8 z = (s16x8)(short)0;
                *(s16x8*)&As[arow][aseg]     = z;
                *(s16x8*)&As[arow][aseg + 8] = z;
            }
        }
        {
            int n  = tid >> 2;
            int ks = (tid & 3) * 8;
            *(s16x8*)&Bs[n][ks] = *(const s16x8*)&Bt[(size_t)n * K + k0 + ks];
        }
        __syncthreads();

        s16x8 av_[2];
#pragma unroll
        for (int mi = 0; mi < 2; ++mi)
            av_[mi] = *(const s16x8*)&As[wm + mi * 16 + mr][kg];
#pragma unroll
        for (int ni = 0; ni < 4; ++ni) {
            s16x8 bhv = *(const s16x8*)&Bs[ni * 16 + mr][kg];
#pragma unroll
            for (int mi = 0; mi < 2; ++mi)
                acc[mi][ni] = __builtin_amdgcn_mfma_f32_16x16x32_bf16(av_[mi], bhv, acc[mi][ni], 0, 0, 0);
        }
        __syncthreads();
    }

    float av[4], rv[4];
#pragma unroll
    for (int ni = 0; ni < 4; ++ni) {
        int c = ni * 16 + mr;
        av[ni] = al[c];
        rv[ni] = ar[c];
    }

#pragma unroll
    for (int mi = 0; mi < 2; ++mi) {
#pragma unroll
        for (int r4 = 0; r4 < 4; ++r4) {
            int rr = row0 + wm + mi * 16 + (lane >> 4) * 4 + r4;
            if (rr < M) {
#pragma unroll
                for (int ni = 0; ni < 4; ++ni)
                    C[(size_t)rr * 64 + ni * 16 + mr] = __float2half(acc[mi][ni][r4]);
            }
            float e0 = 0.f, f0 = 0.f;
#pragma unroll
            for (int ni = 0; ni < 4; ++ni) {
                e0 += acc[mi][ni][r4] * av[ni];
                f0 += acc[mi][ni][r4] * rv[ni];
            }
#pragma unroll
            for (int o = 1; o <= 8; o <<= 1) {
                e0 += __shfl_xor(e0, o);
                f0 += __shfl_xor(f0, o);
            }
            if (mr == 0 && rr < M) { el[rr] = e0; er[rr] = f0; }
        }
    }
}

// ====== fused softmax (no-max) + aggregation, layer 1 (H=4, D=64) ======
__global__ void agg_sm_l1(const __half* __restrict__ feat, const float* __restrict__ el,
                          const float* __restrict__ er, const int* __restrict__ src_sorted,
                          const int* __restrict__ off, const int* __restrict__ deg,
                          const float* __restrict__ bias, short* __restrict__ out) {
    __shared__ float alds[4][MAXDEG * 4];
    int w    = threadIdx.x >> 6;
    int wid  = blockIdx.x * 4 + w;
    int lane = threadIdx.x & 63;
    if (wid >= NN) return;
    int e   = lane >> 5;
    int c8  = (lane & 31) * 8;
    int h   = (lane & 31) >> 3;
    int k   = lane & 7;
    int sub = e * 8 + k;
    int beg = off[wid], dg = deg[wid];
    float erdh = er[(size_t)wid * 4 + h];

    float sum = 0.f;
    for (int p = sub; p < dg; p += 16) {
        int s = src_sorted[beg + p];
        float x = el[(size_t)s * 4 + h] + erdh;
        x = (x >= 0.f) ? x : NEG * x;
        float ex = __expf(x);
        if (p < MAXDEG) alds[w][p * 4 + h] = ex;
        sum += ex;
    }
    sum += __shfl_xor(sum, 1);
    sum += __shfl_xor(sum, 2);
    sum += __shfl_xor(sum, 4);
    sum += __shfl_xor(sum, 32);
    float inv = (dg > 0) ? 1.f / sum : 0.f;

    float acc[8] = {};
    int p = e;
    for (; p + 2 < dg; p += 4) {
        int s0 = src_sorted[beg + p];
        int s1 = src_sorted[beg + p + 2];
        float a0, a1;
        if (p < MAXDEG) a0 = alds[w][p * 4 + h];
        else {
            float x = el[(size_t)s0 * 4 + h] + erdh;
            x = (x >= 0.f) ? x : NEG * x;
            a0 = __expf(x);
        }
        if (p + 2 < MAXDEG) a1 = alds[w][(p + 2) * 4 + h];
        else {
            float x = el[(size_t)s1 * 4 + h] + erdh;
            x = (x >= 0.f) ? x : NEG * x;
            a1 = __expf(x);
        }
        float4 r0 = *(const float4*)&feat[(size_t)s0 * 256 + c8];
        float4 r1 = *(const float4*)&feat[(size_t)s1 * 256 + c8];
        __half2* h0 = (__half2*)&r0;
        __half2* h1 = (__half2*)&r1;
#pragma unroll
        for (int q = 0; q < 4; ++q) {
            float2 f0 = __half22float2(h0[q]);
            float2 f1 = __half22float2(h1[q]);
            acc[2 * q]     += a0 * f0.x + a1 * f1.x;
            acc[2 * q + 1] += a0 * f0.y + a1 * f1.y;
        }
    }
    for (; p < dg; p += 2) {
        int s = src_sorted[beg + p];
        float a;
        if (p < MAXDEG) a = alds[w][p * 4 + h];
        else {
            float x = el[(size_t)s * 4 + h] + erdh;
            x = (x >= 0.f) ? x : NEG * x;
            a = __expf(x);
        }
        float4 raw = *(const float4*)&feat[(size_t)s * 256 + c8];
        __half2* hh = (__half2*)&raw;
#pragma unroll
        for (int q = 0; q < 4; ++q) {
            float2 f = __half22float2(hh[q]);
            acc[2 * q]     += a * f.x;
            acc[2 * q + 1] += a * f.y;
        }
    }
#pragma unroll
    for (int q = 0; q < 8; ++q) acc[q] += __shfl_xor(acc[q], 32);
    if (e == 0) {
        short ob[8];
#pragma unroll
        for (int q = 0; q < 8; ++q) {
            float v = fmaxf(acc[q] * inv + bias[c8 + q], 0.f);
            ob[q] = bf16_rne(v);
        }
        *(s16x8*)&out[(size_t)wid * 256 + c8] = *(s16x8*)&ob[0];
    }
}

// ====== fused softmax (no-max) + aggregation, layer 2 (H=1, D=64) ======
__global__ void agg_sm_l2(const __half* __restrict__ feat, const float* __restrict__ el,
                          const float* __restrict__ er, const int* __restrict__ src_sorted,
                          const int* __restrict__ off, const int* __restrict__ deg,
                          const float* __restrict__ bias, float* __restrict__ out) {
    __shared__ float alds[4][MAXDEG];
    int w    = threadIdx.x >> 6;
    int wid  = blockIdx.x * 4 + w;
    int lane = threadIdx.x & 63;
    if (wid >= NN) return;
    int e   = lane >> 3;
    int c8  = (lane & 7) * 8;
    int beg = off[wid], dg = deg[wid];
    float erd = er[wid];

    float sum = 0.f;
    for (int p = lane; p < dg; p += 64) {
        int s = src_sorted[beg + p];
        float x = el[s] + erd;
        x = (x >= 0.f) ? x : NEG * x;
        float ex = __expf(x);
        if (p < MAXDEG) alds[w][p] = ex;
        sum += ex;
    }
#pragma unroll
    for (int o = 1; o <= 32; o <<= 1) sum += __shfl_xor(sum, o);
    float inv = (dg > 0) ? 1.f / sum : 0.f;

    float acc[8] = {};
    for (int p = 0; p < dg; p += 8) {
        if (p + e < dg) {
            int s = src_sorted[beg + p + e];
            float a;
            if (p + e < MAXDEG) a = alds[w][p + e];
            else {
                float x = el[s] + erd;
                x = (x >= 0.f) ? x : NEG * x;
                a = __expf(x);
            }
            float4 raw = *(const float4*)&feat[(size_t)s * 64 + c8];
            __half2* hh = (__half2*)&raw;
#pragma unroll
            for (int q = 0; q < 4; ++q) {
                float2 f = __half22float2(hh[q]);
                acc[2 * q]     += a * f.x;
                acc[2 * q + 1] += a * f.y;
            }
        }
    }
#pragma unroll
    for (int o = 8; o <= 32; o <<= 1)
#pragma unroll
        for (int q = 0; q < 8; ++q) acc[q] += __shfl_xor(acc[q], o);
    if (e == 0) {
        float4 b0 = *(const float4*)&bias[c8];
        float4 b1 = *(const float4*)&bias[c8 + 4];
        float4 o0 = make_float4(acc[0] * inv + b0.x, acc[1] * inv + b0.y,
                                acc[2] * inv + b0.z, acc[3] * inv + b0.w);
        float4 o1 = make_float4(acc[4] * inv + b1.x, acc[5] * inv + b1.y,
                                acc[6] * inv + b1.z, acc[7] * inv + b1.w);
        *(float4*)&out[(size_t)wid * 64 + c8]     = o0;
        *(float4*)&out[(size_t)wid * 64 + c8 + 4] = o1;
    }
}

extern "C" void kernel_launch(void* const* d_in, const int* in_sizes, int n_in,
                              void* d_out, int out_size, void* d_ws, size_t ws_size,
                              hipStream_t stream) {
    const float* features = (const float*)d_in[0];
    const int*   src      = (const int*)  d_in[1];
    const int*   dst      = (const int*)  d_in[2];
    const float* W1       = (const float*)d_in[3];
    const float* al1      = (const float*)d_in[4];
    const float* ar1      = (const float*)d_in[5];
    const float* b1       = (const float*)d_in[6];
    const float* W2       = (const float*)d_in[7];
    const float* al2      = (const float*)d_in[8];
    const float* ar2      = (const float*)d_in[9];
    const float* b2       = (const float*)d_in[10];
    float* out = (float*)d_out;

    // ---- workspace layout (byte offsets) ----
    char* base = (char*)d_ws;
    size_t o = 0;
    __half* feat1h = (__half*)(base + o); o += (size_t)NN * 256 * 2;
    short*  h1b    = (short*) (base + o); o += (size_t)NN * 256 * 2;
    float*  el1 = (float*)(base + o); o += (size_t)NN * 4 * 4;
    float*  er1 = (float*)(base + o); o += (size_t)NN * 4 * 4;
    float*  el2 = (float*)(base + o); o += (size_t)NN * 4;
    float*  er2 = (float*)(base + o); o += (size_t)NN * 4;
    int* deg        = (int*)(base + o); o += (size_t)NN * 4;
    int* off        = (int*)(base + o); o += (size_t)NN * 4;
    int* src_sorted = (int*)(base + o); o += (size_t)NE * 4;
    int* cnt        = (int*)(base + o); o += (size_t)NBUK * NCHK * 4;
    int* buktot     = (int*)(base + o); o += 1024;
    int2* ebufS = (int2*)(base + o); o += (size_t)NE * 8;
    int2* ebufD = (int2*)(base + o); o += (size_t)NE * 8;
    short* Wt1 = (short*)(base + o); o += (size_t)IND * IND * 2;
    short* Wt2 = (short*)(base + o); o += (size_t)OUTD * IND * 2;

    __half* feat2h = feat1h;

    // ---- CSR build (7 launches; weight prep folded into the first) ----
    cnt1a_k<<<NCHK, 256, 0, stream>>>(src, cnt, W1, W2, Wt1, Wt2);
    scanC_k<<<(NBUK + 3) / 4, 256, 0, stream>>>(cnt, buktot);
    fill1a_k<<<NCHK, 256, 0, stream>>>(src, dst, cnt, buktot, ebufS);
    cnt1b_k<<<NCHK, 256, 0, stream>>>(ebufS, cnt);
    scanC_k<<<(NBUK + 3) / 4, 256, 0, stream>>>(cnt, buktot);
    fill1b_k<<<NCHK, 256, 0, stream>>>(ebufS, cnt, buktot, ebufD);
    fill2_k<<<NBUK, 256, 0, stream>>>(ebufD, buktot, off, deg, src_sorted);

    // ======== layer 1 ========
    gemm_l1<<<(NN + 63) / 64, 256, 0, stream>>>(features, Wt1, al1, ar1,
                                                feat1h, el1, er1, NN);
    agg_sm_l1<<<(NN + 3) / 4, 256, 0, stream>>>(feat1h, el1, er1, src_sorted, off, deg,
                                                b1, h1b);

    // ======== layer 2 ========
    gemm_l2<<<(NN + 127) / 128, 256, 0, stream>>>(h1b, Wt2, al2, ar2,
                                                  feat2h, el2, er2, NN);
    agg_sm_l2<<<(NN + 3) / 4, 256, 0, stream>>>(feat2h, el2, er2, src_sorted, off, deg,
                                                b2, out);
}